// Round 1
// baseline (5675.129 us; speedup 1.0000x reference)
//
#include <hip/hip_runtime.h>
#include <hip/hip_bf16.h>

// TSGCN: GCN(2 layers, fused) -> GRU(4096->256) -> GRU(256->256) -> FC head
// B=32 S=512 N=64 F=16 G=64 H=256. All fp32.

#define EPS_BN 1e-5f

// ---------------------------------------------------------------- zero ints
__global__ void k_zero32(int* __restrict__ p, int n) {
  int i = blockIdx.x * 256 + threadIdx.x;
  if (i < n) p[i] = 0;
}

// ------------------------------------------------- pack Whh for GRU kernel
// GRU thread t (0..767) of parity c wants w[i] = Whh[grow][half*128+i],
//   l = t%384, half = t/384, gate = l>>7, jloc = l&127, grow = gate*256 + c + 2*jloc
// Stored as wp[(c*128 + i)*768 + t] so the per-thread load is coalesced.
__global__ void k_pack_whh(const float* __restrict__ whh, float* __restrict__ wp) {
  int idx = blockIdx.x * 256 + threadIdx.x;
  if (idx >= 2 * 128 * 768) return;
  int c = idx / (128 * 768);
  int i = (idx / 768) % 128;
  int t = idx % 768;
  int l = t % 384;
  int half = t / 384;
  int gate = l >> 7;
  int jloc = l & 127;
  int grow = gate * 256 + c + 2 * jloc;
  wp[idx] = whh[grow * 256 + half * 128 + i];
}

// ------------------------------------------------------------- fused GCN
// One block per (b,s). seq row (local) = relu(A@((bn(relu(A@(X@W0)+b0)))@W1)+b1)
__global__ __launch_bounds__(256) void k_gcn(
    const float* __restrict__ x, const float* __restrict__ adj,
    const float* __restrict__ W0, const float* __restrict__ b0,
    const float* __restrict__ W1, const float* __restrict__ b1,
    const float* __restrict__ bn_g, const float* __restrict__ bn_b,
    const float* __restrict__ bn_m, const float* __restrict__ bn_v,
    float* __restrict__ seq, int base)
{
  __shared__ float As[4096];   // adj [64][64]
  __shared__ float Xs[1024];   // x   [64][16]
  __shared__ float Hs[4096];   // h1  [64][64]
  __shared__ float Qs[4096];   // h1@W1 [64][64]
  __shared__ float bnm_s[64], bns_s[64], bnb_s[64];

  const int t = threadIdx.x;
  const int lane = t & 63;     // g column
  const int w = t >> 6;        // wave 0..3
  const int m = base + blockIdx.x;

  { // stage adj + x
    const float4* a4 = (const float4*)adj;
    float4* s4 = (float4*)As;
#pragma unroll
    for (int p = 0; p < 4; ++p) s4[t + 256 * p] = a4[t + 256 * p];
    ((float4*)Xs)[t] = ((const float4*)(x + (size_t)m * 1024))[t];
  }
  if (t < 64) {
    bns_s[t] = rsqrtf(bn_v[t] + EPS_BN) * bn_g[t];
    bnm_s[t] = bn_m[t];
    bnb_s[t] = bn_b[t];
  }
  float w0r[16];
#pragma unroll
  for (int f = 0; f < 16; ++f) w0r[f] = W0[f * 64 + lane];
  const float b0v = b0[lane], b1v = b1[lane];
  __syncthreads();

  // P[v] = (X@W0)[v][lane]  (per-thread column, redundant across waves)
  float p[64];
#pragma unroll
  for (int v = 0; v < 64; ++v) {
    float acc = 0.f;
#pragma unroll
    for (int f = 0; f < 16; ++f) acc += Xs[v * 16 + f] * w0r[f];
    p[v] = acc;
  }
  // H1[u][lane] for u in this wave's 16 rows
#pragma unroll
  for (int uu = 0; uu < 16; ++uu) {
    int u = w * 16 + uu;
    float acc = 0.f;
#pragma unroll
    for (int v = 0; v < 64; ++v) acc += As[u * 64 + v] * p[v];
    float h1 = fmaxf(acc + b0v, 0.f);
    h1 = (h1 - bnm_s[u]) * bns_s[u] + bnb_s[u];
    Hs[u * 64 + lane] = h1;
  }
  __syncthreads();
  float w1r[64];
#pragma unroll
  for (int f = 0; f < 64; ++f) w1r[f] = W1[f * 64 + lane];
  // Q[v][lane] = (H1@W1)[v][lane], v split across waves
#pragma unroll
  for (int vv = 0; vv < 16; ++vv) {
    int v = w * 16 + vv;
    float acc = 0.f;
#pragma unroll
    for (int f = 0; f < 64; ++f) acc += Hs[v * 64 + f] * w1r[f];
    Qs[v * 64 + lane] = acc;
  }
  __syncthreads();
  float q[64];
#pragma unroll
  for (int v = 0; v < 64; ++v) q[v] = Qs[v * 64 + lane];
  float* outrow = seq + (size_t)blockIdx.x * 4096;
#pragma unroll
  for (int uu = 0; uu < 16; ++uu) {
    int u = w * 16 + uu;
    float acc = 0.f;
#pragma unroll
    for (int v = 0; v < 64; ++v) acc += As[u * 64 + v] * q[v];
    outrow[u * 64 + lane] = fmaxf(acc + b1v, 0.f);
  }
}

// --------------------------------------------------------- GEMM  C = A@B^T + bias
// A: [M][K] row-major (local rows), B: [768][K] row-major, C: [rows][768] (pre-offset)
#define BM 128
#define BN 128
#define BKK 16
__global__ __launch_bounds__(256) void k_gemm_nt(
    const float* __restrict__ A, int lda,
    const float* __restrict__ Bm,
    const float* __restrict__ bias,
    float* __restrict__ C,
    int K, int mBlocks)
{
  __shared__ float As[BKK][BM + 4];
  __shared__ float Bs[BKK][BN + 4];
  const int bid = blockIdx.x;
  const int mb = bid % mBlocks;
  const int nb = bid / mBlocks;
  const int m0 = mb * BM, n0 = nb * BN;
  const int t = threadIdx.x;
  const int tx = t & 15, ty = t >> 4;
  const int lr = t >> 2;           // 0..63
  const int lk = (t & 3) * 4;      // 0,4,8,12

  const float* Ap  = A  + (size_t)(m0 + lr) * lda + lk;
  const float* Ap2 = Ap + (size_t)64 * lda;
  const float* Bp  = Bm + (size_t)(n0 + lr) * K + lk;
  const float* Bp2 = Bp + (size_t)64 * K;

  float acc[8][8] = {};
  for (int kt = 0; kt < K; kt += BKK) {
    const float4 a0 = *(const float4*)(Ap + kt);
    const float4 a1 = *(const float4*)(Ap2 + kt);
    const float4 g0 = *(const float4*)(Bp + kt);
    const float4 g1 = *(const float4*)(Bp2 + kt);
    __syncthreads();
    As[lk + 0][lr] = a0.x; As[lk + 1][lr] = a0.y; As[lk + 2][lr] = a0.z; As[lk + 3][lr] = a0.w;
    As[lk + 0][64 + lr] = a1.x; As[lk + 1][64 + lr] = a1.y; As[lk + 2][64 + lr] = a1.z; As[lk + 3][64 + lr] = a1.w;
    Bs[lk + 0][lr] = g0.x; Bs[lk + 1][lr] = g0.y; Bs[lk + 2][lr] = g0.z; Bs[lk + 3][lr] = g0.w;
    Bs[lk + 0][64 + lr] = g1.x; Bs[lk + 1][64 + lr] = g1.y; Bs[lk + 2][64 + lr] = g1.z; Bs[lk + 3][64 + lr] = g1.w;
    __syncthreads();
#pragma unroll
    for (int k = 0; k < BKK; ++k) {
      const float4 av0 = *(const float4*)&As[k][ty * 8];
      const float4 av1 = *(const float4*)&As[k][ty * 8 + 4];
      const float4 bv0 = *(const float4*)&Bs[k][tx * 8];
      const float4 bv1 = *(const float4*)&Bs[k][tx * 8 + 4];
      const float a_[8] = {av0.x, av0.y, av0.z, av0.w, av1.x, av1.y, av1.z, av1.w};
      const float b_[8] = {bv0.x, bv0.y, bv0.z, bv0.w, bv1.x, bv1.y, bv1.z, bv1.w};
#pragma unroll
      for (int im = 0; im < 8; ++im)
#pragma unroll
        for (int jn = 0; jn < 8; ++jn)
          acc[im][jn] += a_[im] * b_[jn];
    }
  }
#pragma unroll
  for (int im = 0; im < 8; ++im) {
    const int mrow = m0 + ty * 8 + im;
    float* crow = C + (size_t)mrow * 768 + n0 + tx * 8;
#pragma unroll
    for (int jn = 0; jn < 8; ++jn)
      crow[jn] = acc[im][jn] + bias[n0 + tx * 8 + jn];
  }
}

// ------------------------------------------------------------------ GRU layer
// 64 blocks = 32 batches x parity c. Block owns all 3 gate rows for h-indices
// j = c + 2*jloc (jloc<128). Weights in VGPRs: thread t: row l=t%384, k-half t/384.
// Per step: reg-dot vs h in LDS -> ghp -> combine (t<128) -> exchange h slice
// with partner block via agent-scope atomics + per-step flags.
__global__ __launch_bounds__(768, 3) void k_gru(
    const float* __restrict__ gi,   // [32*512][768]
    const float* __restrict__ wp,   // packed Whh
    const float* __restrict__ bhh,  // [768]
    float* __restrict__ ys,         // [32*512][256]
    float* __restrict__ hx,         // [32*512][256] exchange buffer
    int* __restrict__ flags)        // [32*512][2]
{
  const int blk = blockIdx.x;
  const int b = blk >> 1;
  const int c = blk & 1;
  const int t = threadIdx.x;
  const int l = t % 384;
  const int half = t / 384;
  const int hbase = half * 128;

  float w[128];
#pragma unroll
  for (int i = 0; i < 128; ++i) w[i] = wp[(c * 128 + i) * 768 + t];

  __shared__ float h_s[256];
  __shared__ float ghp[2][384];
  if (t < 256) h_s[t] = 0.f;

  float br = 0.f, bz = 0.f, bn = 0.f;
  int jj = 0;
  if (t < 128) {
    jj = c + 2 * t;
    br = bhh[jj]; bz = bhh[256 + jj]; bn = bhh[512 + jj];
  }
  __syncthreads();

  for (int step = 0; step < 512; ++step) {
    // partial dot: w . h[half*128 .. +128]
    float acc = 0.f;
#pragma unroll
    for (int i = 0; i < 128; i += 4) {
      const float4 hv = *(const float4*)&h_s[hbase + i];
      acc += w[i] * hv.x + w[i + 1] * hv.y + w[i + 2] * hv.z + w[i + 3] * hv.w;
    }
    ghp[half][l] = acc;
    __syncthreads();

    if (t < 128) {
      const size_t row = (size_t)(b * 512 + step);
      const float hr = ghp[0][t]       + ghp[1][t]       + br;
      const float hz = ghp[0][128 + t] + ghp[1][128 + t] + bz;
      const float hn = ghp[0][256 + t] + ghp[1][256 + t] + bn;
      const float* gib = gi + row * 768;
      const float ir = gib[jj], iz = gib[256 + jj], inn = gib[512 + jj];
      const float r = 1.f / (1.f + expf(-(ir + hr)));
      const float z = 1.f / (1.f + expf(-(iz + hz)));
      const float n = tanhf(inn + r * hn);
      const float hold = h_s[jj];
      const float hnew = (1.f - z) * n + z * hold;
      ys[row * 256 + jj] = hnew;
      __hip_atomic_store(&hx[row * 256 + jj], hnew, __ATOMIC_RELAXED, __HIP_MEMORY_SCOPE_AGENT);
      h_s[jj] = hnew;
    }
    __syncthreads();  // drains vmem: hx stores complete before flag

    const int fbase = (b * 512 + step) * 2;
    if (t == 0) {
      __hip_atomic_store(&flags[fbase + c], 1, __ATOMIC_RELEASE, __HIP_MEMORY_SCOPE_AGENT);
      while (__hip_atomic_load(&flags[fbase + (1 - c)], __ATOMIC_ACQUIRE, __HIP_MEMORY_SCOPE_AGENT) == 0) {
        __builtin_amdgcn_s_sleep(1);
      }
    }
    __syncthreads();

    if (t < 128) {
      const int jp = (1 - c) + 2 * t;
      const size_t row = (size_t)(b * 512 + step);
      h_s[jp] = __hip_atomic_load(&hx[row * 256 + jp], __ATOMIC_RELAXED, __HIP_MEMORY_SCOPE_AGENT);
    }
    __syncthreads();
  }
}

// ------------------------------------------------------------------ FC head
__global__ __launch_bounds__(128) void k_head(
    const float* __restrict__ ys1,
    const float* __restrict__ fc1w, const float* __restrict__ fc1b,
    const float* __restrict__ fc2w, const float* __restrict__ fc2b,
    float* __restrict__ out)
{
  __shared__ float last[256];
  __shared__ float o1[128];
  const int b = blockIdx.x, t = threadIdx.x;
  const float* src = ys1 + (size_t)(b * 512 + 511) * 256;
  last[t] = src[t];
  last[128 + t] = src[128 + t];
  __syncthreads();
  float acc = fc1b[t];
#pragma unroll 8
  for (int k = 0; k < 256; ++k) acc += last[k] * fc1w[k * 128 + t];
  o1[t] = fmaxf(acc, 0.f);
  __syncthreads();
  if (t < 64) {
    float acc2 = fc2b[t];
#pragma unroll 8
    for (int i = 0; i < 128; ++i) acc2 += o1[i] * fc2w[i * 64 + t];
    out[b * 64 + t] = acc2;
  }
}

// ------------------------------------------------------------------ launcher
extern "C" void kernel_launch(void* const* d_in, const int* in_sizes, int n_in,
                              void* d_out, int out_size, void* d_ws, size_t ws_size,
                              hipStream_t stream)
{
  const float* x    = (const float*)d_in[0];
  const float* adj  = (const float*)d_in[1];
  const float* W0   = (const float*)d_in[2];
  const float* b0   = (const float*)d_in[3];
  const float* W1   = (const float*)d_in[4];
  const float* b1   = (const float*)d_in[5];
  const float* bng  = (const float*)d_in[6];
  const float* bnbb = (const float*)d_in[7];
  const float* bnm  = (const float*)d_in[8];
  const float* bnv  = (const float*)d_in[9];
  const float* Wih0 = (const float*)d_in[10];
  const float* Whh0 = (const float*)d_in[11];
  const float* bih0 = (const float*)d_in[12];
  const float* bhh0 = (const float*)d_in[13];
  const float* Wih1 = (const float*)d_in[14];
  const float* Whh1 = (const float*)d_in[15];
  const float* bih1 = (const float*)d_in[16];
  const float* bhh1 = (const float*)d_in[17];
  const float* fc1w = (const float*)d_in[18];
  const float* fc1b = (const float*)d_in[19];
  const float* fc2w = (const float*)d_in[20];
  const float* fc2b = (const float*)d_in[21];
  float* out = (float*)d_out;

  // workspace layout (floats): seqbuf(CHUNK*4096) | gi(16384*768) | ys0(16384*256)
  //                            | hx(16384*256) | wp0 | wp1 | flags(65536 ints)
  float* ws = (float*)d_ws;
  const size_t fixed = (size_t)16384 * 768 + 2 * (size_t)16384 * 256 + 2 * 196608 + 65536;
  int CHUNK = 16384;
  while (CHUNK > 128 && ((size_t)CHUNK * 4096 + fixed) * 4 > ws_size) CHUNK >>= 1;

  size_t off = 0;
  float* seqbuf = ws + off; off += (size_t)CHUNK * 4096;
  float* gi     = ws + off; off += (size_t)16384 * 768;
  float* ys0    = ws + off; off += (size_t)16384 * 256;
  float* hx     = ws + off; off += (size_t)16384 * 256;
  float* wp0    = ws + off; off += 196608;
  float* wp1    = ws + off; off += 196608;
  int*   flags  = (int*)(ws + off);   // 65536 ints (GRU0: first 32768, GRU1: rest)
  float* ys1    = ys0;                // ys0 dead after gi1 GEMM -> reuse

  k_zero32<<<(65536 + 255) / 256, 256, 0, stream>>>(flags, 65536);
  k_pack_whh<<<(196608 + 255) / 256, 256, 0, stream>>>(Whh0, wp0);
  k_pack_whh<<<(196608 + 255) / 256, 256, 0, stream>>>(Whh1, wp1);

  const int nChunks = 16384 / CHUNK;
  for (int ci = 0; ci < nChunks; ++ci) {
    const int base = ci * CHUNK;
    k_gcn<<<CHUNK, 256, 0, stream>>>(x, adj, W0, b0, W1, b1, bng, bnbb, bnm, bnv, seqbuf, base);
    const int mB = CHUNK / BM;
    k_gemm_nt<<<mB * 6, 256, 0, stream>>>(seqbuf, 4096, Wih0, bih0, gi + (size_t)base * 768, 4096, mB);
  }
  k_gru<<<64, 768, 0, stream>>>(gi, wp0, bhh0, ys0, hx, flags);
  k_gemm_nt<<<128 * 6, 256, 0, stream>>>(ys0, 256, Wih1, bih1, gi, 256, 128);
  k_gru<<<64, 768, 0, stream>>>(gi, wp1, bhh1, ys1, hx, flags + 32768);
  k_head<<<32, 128, 0, stream>>>(ys1, fc1w, fc1b, fc2w, fc2b, out);
}